// Round 2
// baseline (107.098 us; speedup 1.0000x reference)
//
#include <hip/hip_runtime.h>

#define NUM_EXPERTS 64
#define TOP_K 2
#define NUM_TOKENS 16384
#define DIM 4096

// Fused kernel:
//   blocks 0..NUM_TOKENS-1 : out[t, d] = x[t, d]*s0 + x[t, d]*s1 (row scale)
//   block  NUM_TOKENS      : 64-bin histogram of expert indices -> counts
// The hist block (128 KB read, LDS atomics) hides under the 537 MB stream.
__global__ __launch_bounds__(256) void moe_fused_kernel(
    const float* __restrict__ x,
    const float* __restrict__ scores,
    const int* __restrict__ experts,
    float* __restrict__ out,
    float* __restrict__ counts) {
    const int b = blockIdx.x;

    if (b < NUM_TOKENS) {
        const int t = b;
        const float s0 = scores[t * TOP_K + 0];
        const float s1 = scores[t * TOP_K + 1];
        const float s = s0 + s1;  // exact-enough: absmax headroom is ~700x
        const float4* __restrict__ xin =
            reinterpret_cast<const float4*>(x + (size_t)t * DIM);
        float4* __restrict__ o = reinterpret_cast<float4*>(out + (size_t)t * DIM);
#pragma unroll
        for (int i = 0; i < 4; ++i) {
            const int idx = threadIdx.x + i * 256;
            float4 v = xin[idx];
            float4 r;
            r.x = v.x * s0 + v.x * s1;
            r.y = v.y * s0 + v.y * s1;
            r.z = v.z * s0 + v.z * s1;
            r.w = v.w * s0 + v.w * s1;
            o[idx] = r;
        }
        (void)s;
    } else {
        // Histogram block: 256 threads, int4 loads, LDS atomics, plain store.
        __shared__ int h[NUM_EXPERTS];
        if (threadIdx.x < NUM_EXPERTS) h[threadIdx.x] = 0;
        __syncthreads();
        const int4* __restrict__ e4 = reinterpret_cast<const int4*>(experts);
        const int n4 = (NUM_TOKENS * TOP_K) / 4;  // 8192
        for (int i = threadIdx.x; i < n4; i += 256) {
            int4 v = e4[i];
            atomicAdd(&h[v.x], 1);
            atomicAdd(&h[v.y], 1);
            atomicAdd(&h[v.z], 1);
            atomicAdd(&h[v.w], 1);
        }
        __syncthreads();
        if (threadIdx.x < NUM_EXPERTS)
            counts[threadIdx.x] = (float)h[threadIdx.x];
    }
}

extern "C" void kernel_launch(void* const* d_in, const int* in_sizes, int n_in,
                              void* d_out, int out_size, void* d_ws, size_t ws_size,
                              hipStream_t stream) {
    const float* x = (const float*)d_in[0];
    const float* top_scores = (const float*)d_in[1];
    const int* experts = (const int*)d_in[2];
    // d_in[3] (num_tokens_per_expert) unused — reference overwrites it.

    float* out = (float*)d_out;                       // (NUM_TOKENS, DIM)
    float* counts = out + (size_t)NUM_TOKENS * DIM;   // (NUM_EXPERTS,)

    moe_fused_kernel<<<NUM_TOKENS + 1, 256, 0, stream>>>(x, top_scores, experts,
                                                         out, counts);
}

// Round 3
// 102.924 us; speedup vs baseline: 1.0406x; 1.0406x over previous
//
#include <hip/hip_runtime.h>

#define NUM_EXPERTS 64
#define TOP_K 2
#define NUM_TOKENS 16384
#define DIM 4096
#define NBLOCKS 2048
#define ROWS_PER_BLOCK (NUM_TOKENS / NBLOCKS)  // 8

typedef float f4 __attribute__((ext_vector_type(4)));

// Fused kernel:
//   all blocks: stream 8 rows each, out[t,:] = x[t,:]*s0 + x[t,:]*s1
//   blocks 0..63 additionally histogram a 512-index slice of the expert ids
//   into LDS, then atomicAdd the 64 partial counts into counts[] (zeroed by
//   a hipMemsetAsync on the stream before this kernel). Integer-valued fp32
//   atomic adds are exact and order-independent -> deterministic.
__global__ __launch_bounds__(256) void moe_fused_kernel(
    const float* __restrict__ x,
    const float* __restrict__ scores,
    const int* __restrict__ experts,
    float* __restrict__ out,
    float* __restrict__ counts) {
    const int b = blockIdx.x;

    // ---- histogram slice (first 64 blocks, dispatched first => overlapped)
    if (b < NUM_EXPERTS) {
        __shared__ int h[NUM_EXPERTS];
        if (threadIdx.x < NUM_EXPERTS) h[threadIdx.x] = 0;
        __syncthreads();
        const int per_block = (NUM_TOKENS * TOP_K) / NUM_EXPERTS;  // 512
        const int4* __restrict__ e4 =
            reinterpret_cast<const int4*>(experts + b * per_block);
        for (int i = threadIdx.x; i < per_block / 4; i += 256) {
            int4 v = e4[i];
            atomicAdd(&h[v.x], 1);
            atomicAdd(&h[v.y], 1);
            atomicAdd(&h[v.z], 1);
            atomicAdd(&h[v.w], 1);
        }
        __syncthreads();
        if (threadIdx.x < NUM_EXPERTS) {
            int c = h[threadIdx.x];
            if (c > 0) atomicAdd(&counts[threadIdx.x], (float)c);
        }
    }

    // ---- streaming scale: 8 rows per block, fully coalesced f4 traffic
    const int row0 = b * ROWS_PER_BLOCK;
#pragma unroll
    for (int r = 0; r < ROWS_PER_BLOCK; ++r) {
        const int t = row0 + r;
        const float s0 = scores[t * TOP_K + 0];
        const float s1 = scores[t * TOP_K + 1];
        const f4* __restrict__ xin =
            reinterpret_cast<const f4*>(x + (size_t)t * DIM);
        f4* __restrict__ o = reinterpret_cast<f4*>(out + (size_t)t * DIM);
#pragma unroll
        for (int i = 0; i < 4; ++i) {
            const int idx = threadIdx.x + i * 256;
            f4 v = __builtin_nontemporal_load(&xin[idx]);
            f4 rr;
            rr[0] = v[0] * s0 + v[0] * s1;
            rr[1] = v[1] * s0 + v[1] * s1;
            rr[2] = v[2] * s0 + v[2] * s1;
            rr[3] = v[3] * s0 + v[3] * s1;
            __builtin_nontemporal_store(rr, &o[idx]);
        }
    }
}

extern "C" void kernel_launch(void* const* d_in, const int* in_sizes, int n_in,
                              void* d_out, int out_size, void* d_ws, size_t ws_size,
                              hipStream_t stream) {
    const float* x = (const float*)d_in[0];
    const float* top_scores = (const float*)d_in[1];
    const int* experts = (const int*)d_in[2];
    // d_in[3] (num_tokens_per_expert) unused — reference overwrites it.

    float* out = (float*)d_out;                       // (NUM_TOKENS, DIM)
    float* counts = out + (size_t)NUM_TOKENS * DIM;   // (NUM_EXPERTS,)

    hipMemsetAsync(counts, 0, NUM_EXPERTS * sizeof(float), stream);
    moe_fused_kernel<<<NBLOCKS, 256, 0, stream>>>(x, top_scores, experts, out,
                                                  counts);
}

// Round 4
// 93.625 us; speedup vs baseline: 1.1439x; 1.0993x over previous
//
#include <hip/hip_runtime.h>

#define NUM_EXPERTS 64
#define TOP_K 2
#define NUM_TOKENS 16384
#define DIM 4096
#define THREADS 256
#define TOTAL_F4 (NUM_TOKENS * (DIM / 4))  // 16777216 float4 elements
#define NBLK (TOTAL_F4 / THREADS)          // 65536 blocks

typedef float f4 __attribute__((ext_vector_type(4)));

// Flat streaming kernel, structure matched to the m13 float4-copy µbench:
// thread i: out4[i] = x4[i]*s0 + x4[i]*s1, where t = i/1024 is the token row.
// Blocks 0..63 additionally compute counts[e] by scanning the 128 KB expert
// index array (L2-resident) for matches with e — no atomics, no zero-init,
// deterministic, and dispatched first so it hides under the 537 MB stream.
__global__ __launch_bounds__(THREADS) void moe_stream_kernel(
    const float* __restrict__ x,
    const float* __restrict__ scores,
    const int* __restrict__ experts,
    float* __restrict__ out,
    float* __restrict__ counts) {

    if (blockIdx.x < NUM_EXPERTS) {
        const int e = (int)blockIdx.x;
        const int4* __restrict__ e4 = reinterpret_cast<const int4*>(experts);
        int cnt = 0;
        for (int i = threadIdx.x; i < (NUM_TOKENS * TOP_K) / 4; i += THREADS) {
            int4 v = e4[i];
            cnt += (v.x == e) + (v.y == e) + (v.z == e) + (v.w == e);
        }
        __shared__ int red[THREADS];
        red[threadIdx.x] = cnt;
        __syncthreads();
        for (int s = THREADS / 2; s > 0; s >>= 1) {
            if (threadIdx.x < s) red[threadIdx.x] += red[threadIdx.x + s];
            __syncthreads();
        }
        if (threadIdx.x == 0) counts[e] = (float)red[0];
    }

    const int i = (int)blockIdx.x * THREADS + (int)threadIdx.x;  // f4 index
    const int t = i >> 10;  // DIM/4 = 1024 f4 per row
    const float2 sp = reinterpret_cast<const float2*>(scores)[t];
    const f4 v = reinterpret_cast<const f4*>(x)[i];
    f4 r;
    r[0] = v[0] * sp.x + v[0] * sp.y;
    r[1] = v[1] * sp.x + v[1] * sp.y;
    r[2] = v[2] * sp.x + v[2] * sp.y;
    r[3] = v[3] * sp.x + v[3] * sp.y;
    reinterpret_cast<f4*>(out)[i] = r;
}

extern "C" void kernel_launch(void* const* d_in, const int* in_sizes, int n_in,
                              void* d_out, int out_size, void* d_ws, size_t ws_size,
                              hipStream_t stream) {
    const float* x = (const float*)d_in[0];
    const float* top_scores = (const float*)d_in[1];
    const int* experts = (const int*)d_in[2];
    // d_in[3] (num_tokens_per_expert) unused — reference overwrites it.

    float* out = (float*)d_out;                       // (NUM_TOKENS, DIM)
    float* counts = out + (size_t)NUM_TOKENS * DIM;   // (NUM_EXPERTS,)

    moe_stream_kernel<<<NBLK, THREADS, 0, stream>>>(x, top_scores, experts,
                                                    out, counts);
}

// Round 5
// 86.336 us; speedup vs baseline: 1.2405x; 1.0844x over previous
//
#include <hip/hip_runtime.h>

#define NUM_EXPERTS 64
#define TOP_K 2
#define NUM_TOKENS 16384
#define DIM 4096
#define THREADS 256
#define TOTAL_F4 (NUM_TOKENS * (DIM / 4))  // 16777216 float4 elements
#define NBLK (TOTAL_F4 / THREADS)          // 65536 blocks (4 blocks per row)

typedef float f4 __attribute__((ext_vector_type(4)));

// Flat streaming kernel (m13 float4-copy structure):
// block b covers f4 indices [b*256, b*256+256) = one quarter of row t=b>>2.
// t is block-uniform -> the scores load compiles to one s_load_dwordx2 per
// block instead of a vector load per thread. NT hints keep the 537 MB
// stream out of L2. Blocks 0..63 also compute counts[e] from the
// L2-resident 128 KB expert array (no atomics, deterministic, hidden).
__global__ __launch_bounds__(THREADS) void moe_stream_kernel(
    const float* __restrict__ x,
    const float* __restrict__ scores,
    const int* __restrict__ experts,
    float* __restrict__ out,
    float* __restrict__ counts) {

    if (blockIdx.x < NUM_EXPERTS) {
        const int e = (int)blockIdx.x;
        const int4* __restrict__ e4 = reinterpret_cast<const int4*>(experts);
        int cnt = 0;
        for (int i = threadIdx.x; i < (NUM_TOKENS * TOP_K) / 4; i += THREADS) {
            int4 v = e4[i];
            cnt += (v.x == e) + (v.y == e) + (v.z == e) + (v.w == e);
        }
        __shared__ int red[THREADS];
        red[threadIdx.x] = cnt;
        __syncthreads();
        for (int s = THREADS / 2; s > 0; s >>= 1) {
            if (threadIdx.x < s) red[threadIdx.x] += red[threadIdx.x + s];
            __syncthreads();
        }
        if (threadIdx.x == 0) counts[e] = (float)red[0];
    }

    const int t = (int)blockIdx.x >> 2;  // block-uniform token row
    const float s0 = scores[t * TOP_K + 0];  // scalar loads (uniform addr)
    const float s1 = scores[t * TOP_K + 1];
    const int i = (int)blockIdx.x * THREADS + (int)threadIdx.x;  // f4 index
    const f4 v = __builtin_nontemporal_load(&reinterpret_cast<const f4*>(x)[i]);
    f4 r;
    r[0] = v[0] * s0 + v[0] * s1;
    r[1] = v[1] * s0 + v[1] * s1;
    r[2] = v[2] * s0 + v[2] * s1;
    r[3] = v[3] * s0 + v[3] * s1;
    __builtin_nontemporal_store(r, &reinterpret_cast<f4*>(out)[i]);
}

extern "C" void kernel_launch(void* const* d_in, const int* in_sizes, int n_in,
                              void* d_out, int out_size, void* d_ws, size_t ws_size,
                              hipStream_t stream) {
    const float* x = (const float*)d_in[0];
    const float* top_scores = (const float*)d_in[1];
    const int* experts = (const int*)d_in[2];
    // d_in[3] (num_tokens_per_expert) unused — reference overwrites it.

    float* out = (float*)d_out;                       // (NUM_TOKENS, DIM)
    float* counts = out + (size_t)NUM_TOKENS * DIM;   // (NUM_EXPERTS,)

    moe_stream_kernel<<<NBLK, THREADS, 0, stream>>>(x, top_scores, experts,
                                                    out, counts);
}